// Round 1
// baseline (81.544 us; speedup 1.0000x reference)
//
#include <hip/hip_runtime.h>
#include <math.h>

#define D 256

// One block per token. 256 threads = 4 waves.
// Wave w handles rows d in [64w, 64w+64); lane ln handles columns [4ln, 4ln+4).
// Single float4 load per (row, lane) feeds both matvec and Frobenius sum.
__global__ __launch_bounds__(256) void rule_transform_kernel(
    const float* __restrict__ hidden,       // [NTOK, D]
    const int*   __restrict__ token_ids,    // [NTOK]
    const float* __restrict__ rules,        // [MAX_RULES, D, D]
    const int*   __restrict__ token_rules,  // [VOCAB]
    float* __restrict__ out)                // [NTOK, D]
{
    const int tok  = blockIdx.x;
    const int t    = threadIdx.x;
    const int wave = t >> 6;
    const int lane = t & 63;

    __shared__ float h_lds[D];
    __shared__ float y_lds[4][D];
    __shared__ float sq_lds[4];

    // Stage hidden vector for this token (1 KB).
    h_lds[t] = hidden[(size_t)tok * D + t];

    const int rule = token_rules[token_ids[tok]];
    const float* __restrict__ M = rules + (size_t)rule * D * D;

    __syncthreads();

    float4 y = {0.f, 0.f, 0.f, 0.f};
    float  sq = 0.f;
    const int d0  = wave << 6;      // wave's first row
    const int col = lane << 2;      // lane's first column

    #pragma unroll 8
    for (int i = 0; i < 64; ++i) {
        const int d = d0 + i;
        const float4 m = *reinterpret_cast<const float4*>(M + (size_t)d * D + col);
        const float hd = h_lds[d];  // LDS broadcast (same addr across wave)
        y.x = fmaf(hd, m.x, y.x);
        y.y = fmaf(hd, m.y, y.y);
        y.z = fmaf(hd, m.z, y.z);
        y.w = fmaf(hd, m.w, y.w);
        sq  = fmaf(m.x, m.x, sq);
        sq  = fmaf(m.y, m.y, sq);
        sq  = fmaf(m.z, m.z, sq);
        sq  = fmaf(m.w, m.w, sq);
    }

    // Wave-level reduce of sq (64 lanes).
    #pragma unroll
    for (int off = 32; off > 0; off >>= 1)
        sq += __shfl_down(sq, off, 64);
    if (lane == 0) sq_lds[wave] = sq;

    // Park this wave's column partials.
    *reinterpret_cast<float4*>(&y_lds[wave][col]) = y;
    __syncthreads();

    const float fro2 = sq_lds[0] + sq_lds[1] + sq_lds[2] + sq_lds[3];
    const float inv  = 1.0f / fmaxf(sqrtf(fro2), 1e-12f);

    const float yy = y_lds[0][t] + y_lds[1][t] + y_lds[2][t] + y_lds[3][t];
    out[(size_t)tok * D + t] = yy * inv;
}

extern "C" void kernel_launch(void* const* d_in, const int* in_sizes, int n_in,
                              void* d_out, int out_size, void* d_ws, size_t ws_size,
                              hipStream_t stream) {
    const float* hidden      = (const float*)d_in[0];
    const int*   token_ids   = (const int*)d_in[1];
    const float* rules       = (const float*)d_in[2];
    const int*   token_rules = (const int*)d_in[3];
    float*       out         = (float*)d_out;

    const int ntok = in_sizes[1];  // B*S

    rule_transform_kernel<<<ntok, 256, 0, stream>>>(
        hidden, token_ids, rules, token_rules, out);
}

// Round 2
// 61.342 us; speedup vs baseline: 1.3293x; 1.3293x over previous
//
#include <hip/hip_runtime.h>
#include <math.h>

#define D 256
#define NRULES 1024
#define TPB 4  // tokens processed per pass over a rule matrix

// ---------------- bookkeeping kernels ----------------

__global__ void zero_counts_kernel(int* __restrict__ counts) {
    counts[threadIdx.x + blockIdx.x * blockDim.x] = 0;
}

__global__ void count_kernel(const int* __restrict__ token_ids,
                             const int* __restrict__ token_rules,
                             int* __restrict__ counts,
                             int* __restrict__ rule_of_token,
                             int ntok) {
    const int i = threadIdx.x + blockIdx.x * blockDim.x;
    if (i >= ntok) return;
    const int r = token_rules[token_ids[i]];
    rule_of_token[i] = r;
    atomicAdd(&counts[r], 1);
}

// Single block, NRULES threads: exclusive scan of counts -> starts, cursor.
__global__ __launch_bounds__(NRULES) void scan_kernel(
    const int* __restrict__ counts,
    int* __restrict__ starts,   // NRULES+1 entries
    int* __restrict__ cursor) {
    __shared__ int tmp[NRULES];
    const int t = threadIdx.x;
    const int v = counts[t];
    tmp[t] = v;
    __syncthreads();
    #pragma unroll
    for (int off = 1; off < NRULES; off <<= 1) {
        const int add = (t >= off) ? tmp[t - off] : 0;
        __syncthreads();
        tmp[t] += add;
        __syncthreads();
    }
    const int incl = tmp[t];
    const int excl = incl - v;
    starts[t] = excl;
    cursor[t] = excl;
    if (t == NRULES - 1) starts[NRULES] = incl;
}

__global__ void scatter_kernel(const int* __restrict__ rule_of_token,
                               int* __restrict__ cursor,
                               int* __restrict__ bucket,
                               int ntok) {
    const int i = threadIdx.x + blockIdx.x * blockDim.x;
    if (i >= ntok) return;
    const int r = rule_of_token[i];
    const int pos = atomicAdd(&cursor[r], 1);
    bucket[pos] = i;
}

// ---------------- main kernel: one block per rule ----------------
// 256 threads = 4 waves. Wave w owns rows [64w,64w+64); lane owns 4 cols.
// Matrix read once per pass; up to TPB tokens share the pass.

__global__ __launch_bounds__(256) void process_kernel(
    const float* __restrict__ hidden,   // [NTOK, D]
    const float* __restrict__ rules,    // [NRULES, D, D]
    const int*   __restrict__ starts,   // [NRULES+1]
    const int*   __restrict__ bucket,   // [NTOK] token ids grouped by rule
    float* __restrict__ out)            // [NTOK, D]
{
    const int r     = blockIdx.x;
    const int start = starts[r];
    const int count = starts[r + 1] - start;
    if (count <= 0) return;

    const int t    = threadIdx.x;
    const int wave = t >> 6;
    const int lane = t & 63;

    __shared__ float h_lds[TPB][D];
    __shared__ float y_lds[TPB][4][D];
    __shared__ float sq_lds[4];
    __shared__ int   toks[TPB];

    const float* __restrict__ M = rules + (size_t)r * D * D;
    const int d0  = wave << 6;
    const int col = lane << 2;

    for (int base = 0; base < count; base += TPB) {
        // stage hidden vectors (zero-pad unused slots)
        if (t < TPB)
            toks[t] = (base + t < count) ? bucket[start + base + t] : -1;
        #pragma unroll
        for (int j = 0; j < TPB; ++j) {
            const int idx = base + j;
            h_lds[j][t] = (idx < count)
                ? hidden[(size_t)bucket[start + idx] * D + t] : 0.f;
        }
        __syncthreads();

        float4 acc[TPB];
        #pragma unroll
        for (int j = 0; j < TPB; ++j) acc[j] = float4{0.f, 0.f, 0.f, 0.f};
        float sq = 0.f;

        #pragma unroll 4
        for (int i = 0; i < 64; ++i) {
            const int d = d0 + i;
            const float4 m = *reinterpret_cast<const float4*>(M + (size_t)d * D + col);
            sq = fmaf(m.x, m.x, fmaf(m.y, m.y, fmaf(m.z, m.z, fmaf(m.w, m.w, sq))));
            #pragma unroll
            for (int j = 0; j < TPB; ++j) {
                const float h = h_lds[j][d];  // LDS broadcast
                acc[j].x = fmaf(h, m.x, acc[j].x);
                acc[j].y = fmaf(h, m.y, acc[j].y);
                acc[j].z = fmaf(h, m.z, acc[j].z);
                acc[j].w = fmaf(h, m.w, acc[j].w);
            }
        }

        // Frobenius reduce (recomputed per pass; matrix identical -> same value)
        #pragma unroll
        for (int off = 32; off > 0; off >>= 1)
            sq += __shfl_down(sq, off, 64);
        if (lane == 0) sq_lds[wave] = sq;

        #pragma unroll
        for (int j = 0; j < TPB; ++j)
            *reinterpret_cast<float4*>(&y_lds[j][wave][col]) = acc[j];
        __syncthreads();

        const float fro2 = sq_lds[0] + sq_lds[1] + sq_lds[2] + sq_lds[3];
        const float inv  = 1.0f / fmaxf(sqrtf(fro2), 1e-12f);

        #pragma unroll
        for (int j = 0; j < TPB; ++j) {
            const int tok = toks[j];
            if (tok >= 0) {
                const float v = (y_lds[j][0][t] + y_lds[j][1][t] +
                                 y_lds[j][2][t] + y_lds[j][3][t]) * inv;
                out[(size_t)tok * D + t] = v;
            }
        }
        __syncthreads();  // protect h_lds/y_lds before next pass
    }
}

// ---------------- launcher ----------------

extern "C" void kernel_launch(void* const* d_in, const int* in_sizes, int n_in,
                              void* d_out, int out_size, void* d_ws, size_t ws_size,
                              hipStream_t stream) {
    const float* hidden      = (const float*)d_in[0];
    const int*   token_ids   = (const int*)d_in[1];
    const float* rules       = (const float*)d_in[2];
    const int*   token_rules = (const int*)d_in[3];
    float*       out         = (float*)d_out;

    const int ntok = in_sizes[1];  // B*S

    int* ws            = (int*)d_ws;
    int* counts        = ws;                    // NRULES
    int* starts        = ws + NRULES;           // NRULES+1
    int* cursor        = ws + 2 * NRULES + 8;   // NRULES
    int* rule_of_token = ws + 3 * NRULES + 16;  // ntok
    int* bucket        = rule_of_token + ntok;  // ntok

    zero_counts_kernel<<<NRULES / 256, 256, 0, stream>>>(counts);
    count_kernel<<<(ntok + 255) / 256, 256, 0, stream>>>(
        token_ids, token_rules, counts, rule_of_token, ntok);
    scan_kernel<<<1, NRULES, 0, stream>>>(counts, starts, cursor);
    scatter_kernel<<<(ntok + 255) / 256, 256, 0, stream>>>(
        rule_of_token, cursor, bucket, ntok);
    process_kernel<<<NRULES, 256, 0, stream>>>(
        hidden, rules, starts, bucket, out);
}

// Round 3
// 54.965 us; speedup vs baseline: 1.4835x; 1.1160x over previous
//
#include <hip/hip_runtime.h>
#include <math.h>

#define D 256
#define NRULES 1024
#define TPB 4        // tokens per pass over a rule matrix
#define NTOK_MAX 4096

// ---------------- prep: one block does count+scan+scatter+worklist ----------------
__global__ __launch_bounds__(1024) void prep_kernel(
    const int* __restrict__ token_ids,    // [ntok]
    const int* __restrict__ token_rules,  // [VOCAB]
    int ntok,
    int* __restrict__ starts,             // [NRULES+1]
    int* __restrict__ bucket,             // [ntok] token indices grouped by rule
    int* __restrict__ worklist,           // [NRULES] non-empty rules, heavy first
    int* __restrict__ nwork)              // [1]
{
    __shared__ int cnt[NRULES];       // histogram -> scan buffer -> cursor
    __shared__ int rtok[NTOK_MAX];    // rule of token i
    __shared__ int wl[NRULES];
    __shared__ int nw;

    const int t = threadIdx.x;
    cnt[t] = 0;
    if (t == 0) nw = 0;
    __syncthreads();

    // histogram + cache rule-per-token
    for (int i = t; i < ntok; i += 1024) {
        const int r = token_rules[token_ids[i]];
        rtok[i] = r;
        atomicAdd(&cnt[r], 1);
    }
    __syncthreads();

    const int c = cnt[t];

    // Hillis-Steele inclusive scan (in place, double barrier per round)
    #pragma unroll
    for (int off = 1; off < NRULES; off <<= 1) {
        const int add = (t >= off) ? cnt[t - off] : 0;
        __syncthreads();
        cnt[t] += add;
        __syncthreads();
    }
    const int incl = cnt[t];
    const int excl = incl - c;
    starts[t] = excl;
    if (t == NRULES - 1) starts[NRULES] = incl;

    // compact worklist: heavy rules (>=2 passes) first
    if (c > TPB) wl[atomicAdd(&nw, 1)] = t;
    __syncthreads();
    if (c > 0 && c <= TPB) wl[atomicAdd(&nw, 1)] = t;

    // convert cnt to cursor
    __syncthreads();
    cnt[t] = excl;
    __syncthreads();

    // scatter tokens into buckets via LDS cursor
    for (int i = t; i < ntok; i += 1024) {
        const int pos = atomicAdd(&cnt[rtok[i]], 1);
        bucket[pos] = i;
    }

    const int nwv = nw;  // valid after the barriers above
    for (int i = t; i < nwv; i += 1024) worklist[i] = wl[i];
    if (t == 0) nwork[0] = nwv;
}

// ---------------- process: one block per non-empty rule ----------------
// 256 threads = 4 waves. Wave w owns rows [64w,64w+64); lane owns 4 cols.
__global__ __launch_bounds__(256) void process_kernel(
    const float* __restrict__ hidden,     // [NTOK, D]
    const float* __restrict__ rules,      // [NRULES, D, D]
    const int*   __restrict__ starts,     // [NRULES+1]
    const int*   __restrict__ bucket,     // [NTOK]
    const int*   __restrict__ worklist,   // [NRULES]
    const int*   __restrict__ nwork,      // [1]
    float* __restrict__ out)              // [NTOK, D]
{
    if ((int)blockIdx.x >= nwork[0]) return;
    const int r     = worklist[blockIdx.x];
    const int start = starts[r];
    const int count = starts[r + 1] - start;

    const int t    = threadIdx.x;
    const int wave = t >> 6;
    const int lane = t & 63;

    __shared__ float h_lds[TPB][D];
    __shared__ float y_lds[TPB][4][D];
    __shared__ float sq_lds[4];
    __shared__ int   toks[TPB];

    const float* __restrict__ M = rules + (size_t)r * D * D;
    const int d0  = wave << 6;
    const int col = lane << 2;

    for (int base = 0; base < count; base += TPB) {
        if (t < TPB)
            toks[t] = (base + t < count) ? bucket[start + base + t] : -1;
        #pragma unroll
        for (int j = 0; j < TPB; ++j) {
            const int idx = base + j;
            h_lds[j][t] = (idx < count)
                ? hidden[(size_t)bucket[start + idx] * D + t] : 0.f;
        }
        __syncthreads();

        float4 acc[TPB];
        #pragma unroll
        for (int j = 0; j < TPB; ++j) acc[j] = float4{0.f, 0.f, 0.f, 0.f};
        float sq = 0.f;

        #pragma unroll 4
        for (int i = 0; i < 64; ++i) {
            const int d = d0 + i;
            const float4 m = *reinterpret_cast<const float4*>(M + (size_t)d * D + col);
            sq = fmaf(m.x, m.x, fmaf(m.y, m.y, fmaf(m.z, m.z, fmaf(m.w, m.w, sq))));
            #pragma unroll
            for (int j = 0; j < TPB; ++j) {
                const float h = h_lds[j][d];  // LDS broadcast
                acc[j].x = fmaf(h, m.x, acc[j].x);
                acc[j].y = fmaf(h, m.y, acc[j].y);
                acc[j].z = fmaf(h, m.z, acc[j].z);
                acc[j].w = fmaf(h, m.w, acc[j].w);
            }
        }

        #pragma unroll
        for (int off = 32; off > 0; off >>= 1)
            sq += __shfl_down(sq, off, 64);
        if (lane == 0) sq_lds[wave] = sq;

        #pragma unroll
        for (int j = 0; j < TPB; ++j)
            *reinterpret_cast<float4*>(&y_lds[j][wave][col]) = acc[j];
        __syncthreads();

        const float fro2 = sq_lds[0] + sq_lds[1] + sq_lds[2] + sq_lds[3];
        const float inv  = 1.0f / fmaxf(sqrtf(fro2), 1e-12f);

        #pragma unroll
        for (int j = 0; j < TPB; ++j) {
            const int tok = toks[j];
            if (tok >= 0) {
                const float v = (y_lds[j][0][t] + y_lds[j][1][t] +
                                 y_lds[j][2][t] + y_lds[j][3][t]) * inv;
                out[(size_t)tok * D + t] = v;
            }
        }
        __syncthreads();
    }
}

// ---------------- launcher ----------------
extern "C" void kernel_launch(void* const* d_in, const int* in_sizes, int n_in,
                              void* d_out, int out_size, void* d_ws, size_t ws_size,
                              hipStream_t stream) {
    const float* hidden      = (const float*)d_in[0];
    const int*   token_ids   = (const int*)d_in[1];
    const float* rules       = (const float*)d_in[2];
    const int*   token_rules = (const int*)d_in[3];
    float*       out         = (float*)d_out;

    const int ntok = in_sizes[1];  // B*S

    int* ws       = (int*)d_ws;
    int* starts   = ws;                      // NRULES+1
    int* bucket   = starts + NRULES + 8;     // ntok
    int* worklist = bucket + ntok;           // NRULES
    int* nwork    = worklist + NRULES;       // 1

    prep_kernel<<<1, 1024, 0, stream>>>(
        token_ids, token_rules, ntok, starts, bucket, worklist, nwork);
    process_kernel<<<NRULES, 256, 0, stream>>>(
        hidden, rules, starts, bucket, worklist, nwork, out);
}

// Round 4
// 51.115 us; speedup vs baseline: 1.5953x; 1.0753x over previous
//
#include <hip/hip_runtime.h>
#include <math.h>

#define D 256
#define NRULES 1024
#define TPB 8        // tokens per pass over a rule matrix
#define NTOK_MAX 4096

// ---------------- prep: one block does count+scan+scatter+worklist ----------------
__global__ __launch_bounds__(1024) void prep_kernel(
    const int* __restrict__ token_ids,    // [ntok]
    const int* __restrict__ token_rules,  // [VOCAB]
    int ntok,
    int* __restrict__ starts,             // [NRULES+1]
    int* __restrict__ bucket,             // [ntok] token indices grouped by rule
    int* __restrict__ worklist,           // [NRULES] non-empty rules, heavy first
    int* __restrict__ nwork)              // [1]
{
    __shared__ int cnt[NRULES];       // histogram -> cursor
    __shared__ int rtok[NTOK_MAX];    // rule of token i
    __shared__ int wl[NRULES];
    __shared__ int wsum[16];
    __shared__ int nw;

    const int t    = threadIdx.x;
    const int wid  = t >> 6;
    const int lane = t & 63;

    cnt[t] = 0;
    if (t == 0) nw = 0;
    __syncthreads();

    // histogram + cache rule-per-token
    for (int i = t; i < ntok; i += 1024) {
        const int r = token_rules[token_ids[i]];
        rtok[i] = r;
        atomicAdd(&cnt[r], 1);
    }
    __syncthreads();

    const int c = cnt[t];

    // wave-level inclusive scan (shfl), then scan of 16 wave sums
    int v = c;
    #pragma unroll
    for (int off = 1; off < 64; off <<= 1) {
        const int u = __shfl_up(v, off, 64);
        if (lane >= off) v += u;
    }
    if (lane == 63) wsum[wid] = v;
    __syncthreads();
    if (t < 16) {
        const int w = wsum[t];
        int s = w;
        #pragma unroll
        for (int off = 1; off < 16; off <<= 1) {
            const int u = __shfl_up(s, off, 16);
            if (t >= off) s += u;
        }
        wsum[t] = s - w;  // exclusive prefix of wave sums
    }
    __syncthreads();

    const int excl = v - c + wsum[wid];
    starts[t] = excl;
    if (t == NRULES - 1) starts[NRULES] = excl + c;
    cnt[t] = excl;  // becomes scatter cursor (only owner touches cnt[t] now)

    // compact worklist: heavy rules (>TPB, i.e. multi-pass) first
    if (c > TPB) wl[atomicAdd(&nw, 1)] = t;
    __syncthreads();
    if (c > 0 && c <= TPB) wl[atomicAdd(&nw, 1)] = t;
    __syncthreads();  // cursor writes + nw final before scatter

    // scatter tokens into buckets via LDS cursor
    for (int i = t; i < ntok; i += 1024) {
        const int pos = atomicAdd(&cnt[rtok[i]], 1);
        bucket[pos] = i;
    }

    const int nwv = nw;
    for (int i = t; i < nwv; i += 1024) worklist[i] = wl[i];
    if (t == 0) nwork[0] = nwv;
}

// ---------------- process: one block per non-empty rule ----------------
// 256 threads = 4 waves. Wave w owns columns [64w, 64w+64).
// Within a wave: rr = lane>>4 picks row-subgroup, cc = lane&15 picks 4 cols.
// Per iteration a wave loads a 4-row x 64-col tile (float4/lane, 1KB/wave).
// y accumulates fully in registers; butterfly shfl over rr at the end.
__global__ __launch_bounds__(256) void process_kernel(
    const float* __restrict__ hidden,     // [NTOK, D]
    const float* __restrict__ rules,      // [NRULES, D, D]
    const int*   __restrict__ starts,     // [NRULES+1]
    const int*   __restrict__ bucket,     // [NTOK]
    const int*   __restrict__ worklist,   // [NRULES]
    const int*   __restrict__ nwork,      // [1]
    float* __restrict__ out)              // [NTOK, D]
{
    if ((int)blockIdx.x >= nwork[0]) return;
    const int r     = worklist[blockIdx.x];
    const int start = starts[r];
    const int count = starts[r + 1] - start;

    const int t    = threadIdx.x;
    const int wave = t >> 6;
    const int lane = t & 63;
    const int rr   = lane >> 4;                       // 0..3 row subgroup
    const int col  = (wave << 6) + ((lane & 15) << 2); // lane's 4 columns

    __shared__ float h_lds[TPB][D];
    __shared__ float sq_lds[4];
    __shared__ int   toks[TPB];

    const float* __restrict__ M = rules + (size_t)r * D * D;

    for (int base = 0; base < count; base += TPB) {
        if (t < TPB)
            toks[t] = (base + t < count) ? bucket[start + base + t] : -1;
        #pragma unroll
        for (int j = 0; j < TPB; ++j) {
            const int idx = base + j;
            h_lds[j][t] = (idx < count)
                ? hidden[(size_t)bucket[start + idx] * D + t] : 0.f;
        }
        __syncthreads();

        float4 acc[TPB];
        #pragma unroll
        for (int j = 0; j < TPB; ++j) acc[j] = float4{0.f, 0.f, 0.f, 0.f};
        float sq = 0.f;

        #pragma unroll 8
        for (int i = 0; i < 64; ++i) {
            const int d = (i << 2) + rr;
            const float4 m = *reinterpret_cast<const float4*>(M + (size_t)d * D + col);
            sq = fmaf(m.x, m.x, fmaf(m.y, m.y, fmaf(m.z, m.z, fmaf(m.w, m.w, sq))));
            #pragma unroll
            for (int j = 0; j < TPB; ++j) {
                const float h = h_lds[j][d];  // 4 addrs/wave, broadcast x16 — conflict-free
                acc[j].x = fmaf(h, m.x, acc[j].x);
                acc[j].y = fmaf(h, m.y, acc[j].y);
                acc[j].z = fmaf(h, m.z, acc[j].z);
                acc[j].w = fmaf(h, m.w, acc[j].w);
            }
        }

        // Frobenius: full-wave reduce, then cross-wave via LDS
        #pragma unroll
        for (int off = 32; off > 0; off >>= 1)
            sq += __shfl_down(sq, off, 64);
        if (lane == 0) sq_lds[wave] = sq;

        // y: butterfly over the 4 row-subgroups (all lanes end with full sum)
        #pragma unroll
        for (int j = 0; j < TPB; ++j) {
            #pragma unroll
            for (int mask = 16; mask < 64; mask <<= 1) {
                acc[j].x += __shfl_xor(acc[j].x, mask, 64);
                acc[j].y += __shfl_xor(acc[j].y, mask, 64);
                acc[j].z += __shfl_xor(acc[j].z, mask, 64);
                acc[j].w += __shfl_xor(acc[j].w, mask, 64);
            }
        }
        __syncthreads();

        const float fro2 = sq_lds[0] + sq_lds[1] + sq_lds[2] + sq_lds[3];
        const float inv  = 1.0f / fmaxf(sqrtf(fro2), 1e-12f);

        // store: row-subgroup g writes tokens j with (j&3)==g (16 lanes x 16B each)
        #pragma unroll
        for (int j = 0; j < TPB; ++j) {
            if (rr == (j & 3)) {
                const int tok = toks[j];
                if (tok >= 0) {
                    float4 o;
                    o.x = acc[j].x * inv; o.y = acc[j].y * inv;
                    o.z = acc[j].z * inv; o.w = acc[j].w * inv;
                    *reinterpret_cast<float4*>(out + (size_t)tok * D + col) = o;
                }
            }
        }
        __syncthreads();  // protect h_lds/toks before next pass
    }
}

// ---------------- launcher ----------------
extern "C" void kernel_launch(void* const* d_in, const int* in_sizes, int n_in,
                              void* d_out, int out_size, void* d_ws, size_t ws_size,
                              hipStream_t stream) {
    const float* hidden      = (const float*)d_in[0];
    const int*   token_ids   = (const int*)d_in[1];
    const float* rules       = (const float*)d_in[2];
    const int*   token_rules = (const int*)d_in[3];
    float*       out         = (float*)d_out;

    const int ntok = in_sizes[1];  // B*S

    int* ws       = (int*)d_ws;
    int* starts   = ws;                      // NRULES+1
    int* bucket   = starts + NRULES + 8;     // ntok
    int* worklist = bucket + ntok;           // NRULES
    int* nwork    = worklist + NRULES;       // 1

    prep_kernel<<<1, 1024, 0, stream>>>(
        token_ids, token_rules, ntok, starts, bucket, worklist, nwork);
    process_kernel<<<NRULES, 256, 0, stream>>>(
        hidden, rules, starts, bucket, worklist, nwork, out);
}

// Round 5
// 50.737 us; speedup vs baseline: 1.6072x; 1.0074x over previous
//
#include <hip/hip_runtime.h>
#include <math.h>

#define D 256
#define NRULES 1024
#define TPB 8     // tokens per pass over a rule matrix
#define KMAX 16   // fixed bucket stride; count>KMAX spills (P ~ 1e-9 at Poisson(2))

// ---------------- prep: fully parallel, no scan ----------------
__global__ void prep_kernel(const int* __restrict__ token_ids,
                            const int* __restrict__ token_rules,
                            int ntok,
                            int* __restrict__ counts,   // [NRULES], pre-zeroed
                            int* __restrict__ bucket,   // [NRULES*KMAX]
                            int* __restrict__ spill,    // [ntok]
                            int* __restrict__ nspill) { // [1], pre-zeroed
    const int i = blockIdx.x * blockDim.x + threadIdx.x;
    if (i >= ntok) return;
    const int r = token_rules[token_ids[i]];
    const int slot = atomicAdd(&counts[r], 1);
    if (slot < KMAX) bucket[r * KMAX + slot] = i;
    else             spill[atomicAdd(nspill, 1)] = (r << 16) | i;
}

// ---------------- shared worker: apply matrix M to `count` tokens ----------------
// 256 threads = 4 waves. Wave w owns columns [64w,64w+64); rr = lane>>4 row-subgroup.
__device__ __forceinline__ void apply_rule(
    const float* __restrict__ M,
    const int* toks,            // LDS, count entries
    int count,
    const float* __restrict__ hidden,
    float* __restrict__ out,
    float (*h_lds)[D], float* sq_lds,
    int t, int wave, int lane, int rr, int col)
{
    for (int base = 0; base < count; base += TPB) {
        #pragma unroll
        for (int j = 0; j < TPB; ++j) {
            const int idx = base + j;
            h_lds[j][t] = (idx < count)
                ? hidden[(size_t)toks[idx] * D + t] : 0.f;
        }
        __syncthreads();

        float4 acc[TPB];
        #pragma unroll
        for (int j = 0; j < TPB; ++j) acc[j] = float4{0.f, 0.f, 0.f, 0.f};
        float sq = 0.f;

        #pragma unroll 8
        for (int i = 0; i < 64; ++i) {
            const int d = (i << 2) + rr;
            const float4 m = *reinterpret_cast<const float4*>(M + (size_t)d * D + col);
            sq = fmaf(m.x, m.x, fmaf(m.y, m.y, fmaf(m.z, m.z, fmaf(m.w, m.w, sq))));
            #pragma unroll
            for (int j = 0; j < TPB; ++j) {
                const float h = h_lds[j][d];  // 4 addrs/wave, x16 broadcast — conflict-free
                acc[j].x = fmaf(h, m.x, acc[j].x);
                acc[j].y = fmaf(h, m.y, acc[j].y);
                acc[j].z = fmaf(h, m.z, acc[j].z);
                acc[j].w = fmaf(h, m.w, acc[j].w);
            }
        }

        // Frobenius: wave reduce, park per-wave
        #pragma unroll
        for (int off = 32; off > 0; off >>= 1)
            sq += __shfl_down(sq, off, 64);
        if (lane == 0) sq_lds[wave] = sq;

        // y: butterfly over the 4 row-subgroups
        #pragma unroll
        for (int j = 0; j < TPB; ++j) {
            #pragma unroll
            for (int mask = 16; mask < 64; mask <<= 1) {
                acc[j].x += __shfl_xor(acc[j].x, mask, 64);
                acc[j].y += __shfl_xor(acc[j].y, mask, 64);
                acc[j].z += __shfl_xor(acc[j].z, mask, 64);
                acc[j].w += __shfl_xor(acc[j].w, mask, 64);
            }
        }
        __syncthreads();

        const float fro2 = sq_lds[0] + sq_lds[1] + sq_lds[2] + sq_lds[3];
        const float inv  = 1.0f / fmaxf(sqrtf(fro2), 1e-12f);

        #pragma unroll
        for (int j = 0; j < TPB; ++j) {
            if (rr == (j & 3) && base + j < count) {
                const int tok = toks[base + j];
                float4 o;
                o.x = acc[j].x * inv; o.y = acc[j].y * inv;
                o.z = acc[j].z * inv; o.w = acc[j].w * inv;
                *reinterpret_cast<float4*>(out + (size_t)tok * D + col) = o;
            }
        }
        __syncthreads();  // protect h_lds before next pass / next apply
    }
}

// ---------------- process: block b == rule b ----------------
__global__ __launch_bounds__(256) void process_kernel(
    const float* __restrict__ hidden,     // [NTOK, D]
    const float* __restrict__ rules,      // [NRULES, D, D]
    const int*   __restrict__ counts,     // [NRULES]
    const int*   __restrict__ bucket,     // [NRULES*KMAX]
    const int*   __restrict__ spill,      // [NTOK]
    const int*   __restrict__ nspill,     // [1]
    float* __restrict__ out)              // [NTOK, D]
{
    const int b    = blockIdx.x;
    const int t    = threadIdx.x;
    const int wave = t >> 6;
    const int lane = t & 63;
    const int rr   = lane >> 4;
    const int col  = (wave << 6) + ((lane & 15) << 2);

    __shared__ float h_lds[TPB][D];
    __shared__ float sq_lds[4];
    __shared__ int   toks[KMAX];

    const int cnt = min(counts[b], KMAX);
    if (cnt > 0) {
        if (t < cnt) toks[t] = bucket[b * KMAX + t];
        __syncthreads();
        apply_rule(rules + (size_t)b * D * D, toks, cnt,
                   hidden, out, h_lds, sq_lds, t, wave, lane, rr, col);
    }

    // rare overflow tokens: one block per spill entry, single-token pass
    const int ns = nspill[0];
    for (int k = b; k < ns; k += gridDim.x) {
        __syncthreads();
        const int e = spill[k];
        if (t == 0) toks[0] = e & 0xFFFF;
        __syncthreads();
        apply_rule(rules + (size_t)(e >> 16) * D * D, toks, 1,
                   hidden, out, h_lds, sq_lds, t, wave, lane, rr, col);
    }
}

// ---------------- launcher ----------------
extern "C" void kernel_launch(void* const* d_in, const int* in_sizes, int n_in,
                              void* d_out, int out_size, void* d_ws, size_t ws_size,
                              hipStream_t stream) {
    const float* hidden      = (const float*)d_in[0];
    const int*   token_ids   = (const int*)d_in[1];
    const float* rules       = (const float*)d_in[2];
    const int*   token_rules = (const int*)d_in[3];
    float*       out         = (float*)d_out;

    const int ntok = in_sizes[1];  // B*S

    int* ws     = (int*)d_ws;
    int* counts = ws;                        // NRULES
    int* nspill = ws + NRULES;               // 1 (padded to 8)
    int* bucket = ws + NRULES + 8;           // NRULES*KMAX
    int* spill  = bucket + NRULES * KMAX;    // ntok

    hipMemsetAsync(counts, 0, (NRULES + 8) * sizeof(int), stream);
    prep_kernel<<<(ntok + 255) / 256, 256, 0, stream>>>(
        token_ids, token_rules, ntok, counts, bucket, spill, nspill);
    process_kernel<<<NRULES, 256, 0, stream>>>(
        hidden, rules, counts, bucket, spill, nspill, out);
}